// Round 8
// baseline (385.076 us; speedup 1.0000x reference)
//
#include <hip/hip_runtime.h>
#include <cstdint>
#include <cstddef>

// Dims (fixed by the problem)
#define BB 8
#define CC 128
#define C3 384
#define HH 64
#define H2 32
#define NPIX 1024   // 32*32
#define N4 4096     // 64*64
#define NHD 8
#define HD 16

typedef _Float16 h2f __attribute__((ext_vector_type(2)));
typedef _Float16 h4f __attribute__((ext_vector_type(4)));
typedef float f4 __attribute__((ext_vector_type(4)));

union U4H { uint4 u; h2f h[4]; };
union H4U { h4f v; h2f h[2]; };

__device__ inline h2f pkrtz(float a, float b) {
  return __builtin_bit_cast(h2f, __builtin_amdgcn_cvt_pkrtz(a, b));
}

// ---------------- K1: Haar DWT ----------------
__global__ __launch_bounds__(256) void k_dwt(const float* __restrict__ x,
                                             float* __restrict__ ll,
                                             float* __restrict__ high) {
  int idx = blockIdx.x * 256 + threadIdx.x;   // B*C*32*32 = 1,048,576
  int w = idx & 31, h = (idx >> 5) & 31, c = (idx >> 10) & 127, b = idx >> 17;
  const float* xp = x + ((size_t)(b * CC + c) * HH + 2 * h) * HH + 2 * w;
  float x1 = xp[0];
  float x2 = xp[HH];
  float x3 = xp[1];
  float x4 = xp[HH + 1];
  int n = h * H2 + w;
  ll[(size_t)(b * CC + c) * NPIX + n]              = 0.5f * ( x1 + x2 + x3 + x4);
  high[((size_t)b * C3 + c) * NPIX + n]            = 0.5f * (-x1 - x2 + x3 + x4);
  high[((size_t)b * C3 + CC + c) * NPIX + n]       = 0.5f * (-x1 + x2 - x3 + x4);
  high[((size_t)b * C3 + 2 * CC + c) * NPIX + n]   = 0.5f * ( x1 - x2 - x3 + x4);
}

// ---------------- conv1x1: register GEMV; OPT outs x P pixels per thread ----
template <int CIN, int P, int OPT>
__global__ __launch_bounds__(256) void k_conv1x1(const float* __restrict__ in,
                                                 const float* __restrict__ w,
                                                 float* __restrict__ out,
                                                 int Cout, int Npix) {
  int tid = threadIdx.x;
  int n0 = (blockIdx.x * 256 + tid) * P;
  int o0 = blockIdx.y * OPT;
  int b = blockIdx.z;
  const float* inb = in + (size_t)b * CIN * Npix + n0;
  const float* wb = w + (size_t)o0 * CIN;
  float acc[OPT][P];
#pragma unroll
  for (int o = 0; o < OPT; ++o)
#pragma unroll
    for (int p = 0; p < P; ++p) acc[o][p] = 0.f;

  for (int c0 = 0; c0 < CIN; c0 += 8) {
#pragma unroll
    for (int c = 0; c < 8; ++c) {
      float vv[P];
      const float* ip = inb + (size_t)(c0 + c) * Npix;
      if constexpr (P == 4) {
        float4 t = *(const float4*)ip;
        vv[0] = t.x; vv[1] = t.y; vv[2] = t.z; vv[3] = t.w;
      } else if constexpr (P == 2) {
        float2 t = *(const float2*)ip;
        vv[0] = t.x; vv[1] = t.y;
      } else {
        vv[0] = ip[0];
      }
#pragma unroll
      for (int o = 0; o < OPT; ++o) {
        float wc = wb[(size_t)o * CIN + c0 + c];   // uniform -> s_load
#pragma unroll
        for (int p = 0; p < P; ++p) acc[o][p] = fmaf(wc, vv[p], acc[o][p]);
      }
    }
  }
  size_t ob = ((size_t)b * Cout + o0) * Npix + n0;
#pragma unroll
  for (int o = 0; o < OPT; ++o) {
    float* op = out + ob + (size_t)o * Npix;
    if constexpr (P == 4) {
      *(float4*)op = make_float4(acc[o][0], acc[o][1], acc[o][2], acc[o][3]);
    } else if constexpr (P == 2) {
      *(float2*)op = make_float2(acc[o][0], acc[o][1]);
    } else {
      op[0] = acc[o][0];
    }
  }
}

// ---------------- K2b: split qkv + l2norm q,k -> fp16; V -> transposed vt ----
__global__ __launch_bounds__(256) void k_qkvnorm(const float* __restrict__ qkv,
                                                 uint4* __restrict__ qh,
                                                 uint4* __restrict__ kh,
                                                 uint16_t* __restrict__ vt) {
  __shared__ uint16_t lds_v[16 * 256];
  int tid = threadIdx.x;
  int idx = blockIdx.x * 256 + tid;  // 65536 = B*NH*NPIX
  int n = idx & 1023, h = (idx >> 10) & 7, b = idx >> 13;
  const float* base = qkv + ((size_t)b * C3 + h * HD) * NPIX + n;
  float q[HD], k[HD], vv[HD];
  float sq = 0.f, sk = 0.f;
#pragma unroll
  for (int d = 0; d < HD; ++d) {
    q[d] = base[(size_t)d * NPIX];
    k[d] = base[(size_t)(CC + d) * NPIX];
    vv[d] = base[(size_t)(2 * CC + d) * NPIX];
    sq += q[d] * q[d];
    sk += k[d] * k[d];
  }
  float rq = 1.f / fmaxf(sqrtf(sq), 1e-12f);
  float rk = 1.f / fmaxf(sqrtf(sk), 1e-12f);
#pragma unroll
  for (int g = 0; g < 2; ++g) {
    U4H pq, pk;
#pragma unroll
    for (int d = 0; d < 4; ++d) {
      int e = g * 8 + 2 * d;
      pq.h[d] = pkrtz(q[e] * rq, q[e + 1] * rq);
      pk.h[d] = pkrtz(k[e] * rk, k[e + 1] * rk);
    }
    qh[(size_t)idx * 2 + g] = pq.u;
    kh[(size_t)idx * 2 + g] = pk.u;
  }
  // V: LDS transpose (256 n  x 16 dims -> 16 rows x 256 n)
#pragma unroll
  for (int d = 0; d < HD; ++d) {
    union { _Float16 f; uint16_t u; } cv;
    cv.f = (_Float16)vv[d];
    lds_v[d * 256 + tid] = cv.u;
  }
  __syncthreads();
  int bh = idx >> 10;                      // block-uniform
  int n0 = (blockIdx.x * 256) & 1023;      // block-uniform
  const uint32_t* ldw = (const uint32_t*)lds_v;
  uint32_t* vtw = (uint32_t*)(vt + (size_t)bh * 16384 + n0);
#pragma unroll
  for (int r = 0; r < 8; ++r) {
    int d = 2 * r + (tid >> 7);
    int c = tid & 127;
    vtw[(size_t)d * 512 + c] = ldw[d * 128 + c];
  }
}

// ---------------- K3: sparse top-k attention via MFMA, 4-wave split-K ----
// (verified round-5 kernel, unchanged)
__global__ __launch_bounds__(256) void k_attn(const uint16_t* __restrict__ qh,
                                              const uint16_t* __restrict__ kh,
                                              const uint16_t* __restrict__ vt,
                                              float* __restrict__ attn_out) {
  __shared__ int cnt_lds[12 * 64];     // [it][lm][w]
  __shared__ float sum_lds[64];        // [lm][w]
  __shared__ f4 obuf[4 * 64];          // [w][lane]
  int tid = threadIdx.x;
  int lane = tid & 63;
  int w = tid >> 6;
  int blk = blockIdx.x;                // 4096 blocks: 64 per (b,h)
  int bh = blk >> 6;
  int q0 = (blk & 63) << 4;
  int lm = lane & 15;
  int lg = lane >> 4;
  int b = bh >> 3, h = bh & 7;

  H4U bq;
  bq.v = *(const h4f*)(qh + ((size_t)bh * 1024 + q0 + lm) * 16 + 4 * lg);
  const h2f qsc = {(_Float16)0.25f, (_Float16)0.25f};
  bq.h[0] *= qsc;
  bq.h[1] *= qsc;

  const f4 z = {0.f, 0.f, 0.f, 0.f};
  const uint16_t* kbase = kh + (size_t)bh * 16384 + 4 * lg;
  h2f sc[16][2];
#pragma unroll
  for (int j = 0; j < 16; ++j) {
    int J = (w << 4) | j;
    h4f ak = *(const h4f*)(kbase + (size_t)(16 * J + lm) * 16); // A[m=krow][k=hd]
    f4 d = __builtin_amdgcn_mfma_f32_16x16x16f16(ak, bq.v, z, 0, 0, 0);
    sc[j][0] = pkrtz(d[0], d[1]);
    sc[j][1] = pkrtz(d[2], d[3]);
  }

  float lo = -0.26f, hi = 0.26f;
  _Float16 hlo = (_Float16)(-0.26f);
#pragma unroll 1
  for (int it = 0; it < 12; ++it) {
    float mid = 0.5f * (lo + hi);
    _Float16 hm = (_Float16)mid;
    int c = 0;
#pragma unroll
    for (int j = 0; j < 16; ++j) {
      c += (sc[j][0][0] >= hm);
      c += (sc[j][0][1] >= hm);
      c += (sc[j][1][0] >= hm);
      c += (sc[j][1][1] >= hm);
    }
    c += __shfl_xor(c, 16);
    c += __shfl_xor(c, 32);
    if (lg == 0) cnt_lds[it * 64 + lm * 4 + w] = c;
    __syncthreads();
    int4 c4 = *(const int4*)&cnt_lds[it * 64 + lm * 4];
    int ct = (c4.x + c4.y) + (c4.z + c4.w);
    bool ge = (ct >= 512);
    lo = ge ? mid : lo;
    hlo = ge ? hm : hlo;
    hi = ge ? hi : mid;
  }

  float ss = 0.f;
#pragma unroll
  for (int j = 0; j < 16; ++j) {
#pragma unroll
    for (int r = 0; r < 2; ++r) {
      h2f t = sc[j][r];
      float p0 = (t[0] >= hlo) ? __expf((float)t[0]) : 0.f;
      float p1 = (t[1] >= hlo) ? __expf((float)t[1]) : 0.f;
      ss += p0 + p1;
      sc[j][r] = pkrtz(p0, p1);
    }
  }
  ss += __shfl_xor(ss, 16);
  ss += __shfl_xor(ss, 32);
  if (lg == 0) sum_lds[lm * 4 + w] = ss;
  __syncthreads();
  float4 s4 = *(const float4*)&sum_lds[lm * 4];
  float inv = 1.f / ((s4.x + s4.y) + (s4.z + s4.w));

  const uint16_t* vbase = vt + (size_t)bh * 16384 + (size_t)lm * 1024 + 4 * lg;
  f4 acc[2] = {z, z};
#pragma unroll
  for (int j = 0; j < 16; ++j) {
    int J = (w << 4) | j;
    h4f va = *(const h4f*)(vbase + 16 * J);   // A[m=dim][k=krow]
    H4U pf;
    pf.h[0] = sc[j][0];
    pf.h[1] = sc[j][1];                        // B[k=krow][n=q]
    acc[j & 1] = __builtin_amdgcn_mfma_f32_16x16x16f16(va, pf.v, acc[j & 1], 0, 0, 0);
  }
  f4 o = acc[0] + acc[1];
  obuf[(w << 6) | lane] = o;
  __syncthreads();
  if (w == 0) {
    f4 t = obuf[lane] + obuf[64 + lane] + obuf[128 + lane] + obuf[192 + lane];
#pragma unroll
    for (int e = 0; e < 4; ++e) {
      int dim = 4 * lg + e;
      attn_out[((size_t)(b * CC + h * HD + dim) * NPIX) + q0 + lm] = t[e] * inv;
    }
  }
}

// ---------------- fused proj conv (128->4 of 128) + GN + ll residual -------
// grid 256 (b = blk&7, g = blk>>3), 1024 threads, 1 px/thread.
__global__ __launch_bounds__(1024) void k_projgn(const float* __restrict__ in,
                                                 const float* __restrict__ w,
                                                 const float* __restrict__ res,
                                                 float* __restrict__ out,
                                                 const float* __restrict__ gamma,
                                                 const float* __restrict__ beta) {
  __shared__ float wl[4 * 128];    // 2 KB
  __shared__ float sred[16], s2red[16];
  int blk = blockIdx.x;
  int b = blk & 7, g = blk >> 3;
  int tid = threadIdx.x;
  int c0 = g * 4;
  const float* wsrc = w + (size_t)c0 * CC;
  if (tid < 512) wl[tid] = wsrc[tid];
  __syncthreads();
  const float* inb = in + (size_t)b * CC * NPIX + tid;
  float acc[4] = {0.f, 0.f, 0.f, 0.f};
#pragma unroll 8
  for (int c = 0; c < 128; ++c) {
    float v = inb[(size_t)c * NPIX];
#pragma unroll
    for (int o = 0; o < 4; ++o) acc[o] = fmaf(wl[o * 128 + c], v, acc[o]);
  }
  float s = 0.f, s2 = 0.f;
#pragma unroll
  for (int o = 0; o < 4; ++o) { s += acc[o]; s2 += acc[o] * acc[o]; }
#pragma unroll
  for (int off = 32; off > 0; off >>= 1) {
    s += __shfl_xor(s, off);
    s2 += __shfl_xor(s2, off);
  }
  int wv = tid >> 6;
  if ((tid & 63) == 0) { sred[wv] = s; s2red[wv] = s2; }
  __syncthreads();
  float st = 0.f, s2t = 0.f;
#pragma unroll
  for (int k = 0; k < 16; ++k) { st += sred[k]; s2t += s2red[k]; }
  float inv_n = 1.f / 4096.f;
  float mean = st * inv_n;
  float var = s2t * inv_n - mean * mean;
  float rstd = rsqrtf(var + 1e-6f);
#pragma unroll
  for (int o = 0; o < 4; ++o) {
    size_t base = ((size_t)b * CC + c0 + o) * NPIX + tid;
    out[base] = res[base] + ((acc[o] - mean) * rstd * gamma[c0 + o] + beta[c0 + o]);
  }
}

// ---------------- fused depthwise 3x3 + GN + SiLU (512 thr, 2 px/thread) ----
__global__ __launch_bounds__(512) void k_dwgn(const float* __restrict__ in,
                                              const float* __restrict__ w,
                                              float* __restrict__ out,
                                              const float* __restrict__ gamma,
                                              const float* __restrict__ beta) {
  __shared__ float xs[12 * 1152];      // 12 ch x 32 rows x 36 stride = 55.3 KB
  __shared__ float sred[8], s2red[8];
  int blk = blockIdx.x;
  int b = blk & 7, g = blk >> 3;
  int tid = threadIdx.x;
  int c0 = g * 12;
  const float* inb = in + ((size_t)b * C3 + c0) * NPIX;
  // stage: 12288 floats = 6 f4/thread, scatter to padded rows
#pragma unroll
  for (int k = 0; k < 6; ++k) {
    int e = (k * 512 + tid) * 4;
    int cc = e >> 10, rem = e & 1023;
    int row = rem >> 5, col = rem & 31;
    float4 v = *(const float4*)(inb + e);
    *(float4*)&xs[cc * 1152 + row * 36 + col] = v;
  }
  __syncthreads();
  int n0 = tid * 2;
  int i = n0 >> 5, j0 = n0 & 31;
  float acc[12][2];
  float s = 0.f, s2 = 0.f;
#pragma unroll
  for (int cc = 0; cc < 12; ++cc) {
    const float* wc = w + (size_t)(c0 + cc) * 9;
    float w0 = wc[0], w1 = wc[1], w2 = wc[2], w3 = wc[3], w4 = wc[4],
          w5 = wc[5], w6 = wc[6], w7 = wc[7], w8 = wc[8];
    float r[3][4];
#pragma unroll
    for (int di = 0; di < 3; ++di) {
      int ii = i + di - 1;
      bool rv = (ii >= 0 && ii < 32);
#pragma unroll
      for (int dj = 0; dj < 4; ++dj) {
        int jj = j0 + dj - 1;
        r[di][dj] = (rv && jj >= 0 && jj < 32) ? xs[cc * 1152 + ii * 36 + jj] : 0.f;
      }
    }
#pragma unroll
    for (int p = 0; p < 2; ++p) {
      float a = r[0][p] * w0 + r[0][p + 1] * w1 + r[0][p + 2] * w2
              + r[1][p] * w3 + r[1][p + 1] * w4 + r[1][p + 2] * w5
              + r[2][p] * w6 + r[2][p + 1] * w7 + r[2][p + 2] * w8;
      acc[cc][p] = a;
      s += a;
      s2 += a * a;
    }
  }
  // block reduce (8 waves)
#pragma unroll
  for (int off = 32; off > 0; off >>= 1) {
    s += __shfl_xor(s, off);
    s2 += __shfl_xor(s2, off);
  }
  int wv = tid >> 6;
  if ((tid & 63) == 0) { sred[wv] = s; s2red[wv] = s2; }
  __syncthreads();
  float st = 0.f, s2t = 0.f;
#pragma unroll
  for (int k = 0; k < 8; ++k) { st += sred[k]; s2t += s2red[k]; }
  float inv_n = 1.f / 12288.f;
  float mean = st * inv_n;
  float var = s2t * inv_n - mean * mean;
  float rstd = rsqrtf(var + 1e-6f);
#pragma unroll
  for (int cc = 0; cc < 12; ++cc) {
    float2 o;
#pragma unroll
    for (int p = 0; p < 2; ++p) {
      float gnv = (acc[cc][p] - mean) * rstd * gamma[c0 + cc] + beta[c0 + cc];
      ((float*)&o)[p] = gnv / (1.f + __expf(-gnv));   // silu
    }
    *(float2*)(out + ((size_t)b * C3 + c0 + cc) * NPIX + n0) = o;
  }
}

// ---------------- fused pw conv (384->12 of 384) + GN + alpha residual ------
// grid 256 (b = blk&7, g = blk>>3), 1024 threads, 1 px/thread.
__global__ __launch_bounds__(1024) void k_pwgn(const float* __restrict__ in,
                                               const float* __restrict__ w,
                                               const float* __restrict__ res,
                                               float* __restrict__ out,
                                               const float* __restrict__ gamma,
                                               const float* __restrict__ beta,
                                               const float* __restrict__ alpha_ptr) {
  __shared__ float wl[12 * 384];   // 18 KB
  __shared__ float sred[16], s2red[16];
  int blk = blockIdx.x;
  int b = blk & 7, g = blk >> 3;
  int tid = threadIdx.x;
  int c0 = g * 12;
  const float* wsrc = w + (size_t)c0 * C3;
  for (int k = tid; k < 12 * 384; k += 1024) wl[k] = wsrc[k];
  __syncthreads();
  const float* inb = in + (size_t)b * C3 * NPIX + tid;
  float acc[12];
#pragma unroll
  for (int o = 0; o < 12; ++o) acc[o] = 0.f;
#pragma unroll 4
  for (int c = 0; c < 384; ++c) {
    float v = inb[(size_t)c * NPIX];
#pragma unroll
    for (int o = 0; o < 12; ++o) acc[o] = fmaf(wl[o * 384 + c], v, acc[o]);
  }
  float s = 0.f, s2 = 0.f;
#pragma unroll
  for (int o = 0; o < 12; ++o) { s += acc[o]; s2 += acc[o] * acc[o]; }
#pragma unroll
  for (int off = 32; off > 0; off >>= 1) {
    s += __shfl_xor(s, off);
    s2 += __shfl_xor(s2, off);
  }
  int wv = tid >> 6;
  if ((tid & 63) == 0) { sred[wv] = s; s2red[wv] = s2; }
  __syncthreads();
  float st = 0.f, s2t = 0.f;
#pragma unroll
  for (int k = 0; k < 16; ++k) { st += sred[k]; s2t += s2red[k]; }
  float inv_n = 1.f / 12288.f;
  float mean = st * inv_n;
  float var = s2t * inv_n - mean * mean;
  float rstd = rsqrtf(var + 1e-6f);
  float a = alpha_ptr[0];
#pragma unroll
  for (int o = 0; o < 12; ++o) {
    size_t base = ((size_t)b * C3 + c0 + o) * NPIX + tid;
    out[base] = res[base] + a * ((acc[o] - mean) * rstd * gamma[c0 + o] + beta[c0 + o]);
  }
}

// ---------------- fused ffn conv1 (128->8 of 256) + GN + GELU ----------------
// grid 256 (b = blk&7, g = blk>>3), 1024 threads, 4 px/thread.
__global__ __launch_bounds__(1024) void k_ffn1(const float* __restrict__ in,
                                               const float* __restrict__ w,
                                               float* __restrict__ out,
                                               const float* __restrict__ gamma,
                                               const float* __restrict__ beta) {
  __shared__ float wl[8 * 128];    // 4 KB
  __shared__ float sred[16], s2red[16];
  int blk = blockIdx.x;
  int b = blk & 7, g = blk >> 3;
  int tid = threadIdx.x;
  int c0 = g * 8;
  const float* wsrc = w + (size_t)c0 * CC;
  if (tid < 1024) wl[tid] = wsrc[tid];
  __syncthreads();
  const float* inb = in + (size_t)b * CC * N4 + tid * 4;
  float acc[8][4];
#pragma unroll
  for (int o = 0; o < 8; ++o)
#pragma unroll
    for (int p = 0; p < 4; ++p) acc[o][p] = 0.f;
#pragma unroll 4
  for (int c = 0; c < 128; ++c) {
    float4 v = *(const float4*)(inb + (size_t)c * N4);
#pragma unroll
    for (int o = 0; o < 8; ++o) {
      float wv = wl[o * 128 + c];
      acc[o][0] = fmaf(wv, v.x, acc[o][0]);
      acc[o][1] = fmaf(wv, v.y, acc[o][1]);
      acc[o][2] = fmaf(wv, v.z, acc[o][2]);
      acc[o][3] = fmaf(wv, v.w, acc[o][3]);
    }
  }
  float s = 0.f, s2 = 0.f;
#pragma unroll
  for (int o = 0; o < 8; ++o)
#pragma unroll
    for (int p = 0; p < 4; ++p) { s += acc[o][p]; s2 += acc[o][p] * acc[o][p]; }
#pragma unroll
  for (int off = 32; off > 0; off >>= 1) {
    s += __shfl_xor(s, off);
    s2 += __shfl_xor(s2, off);
  }
  int wv = tid >> 6;
  if ((tid & 63) == 0) { sred[wv] = s; s2red[wv] = s2; }
  __syncthreads();
  float st = 0.f, s2t = 0.f;
#pragma unroll
  for (int k = 0; k < 16; ++k) { st += sred[k]; s2t += s2red[k]; }
  float inv_n = 1.f / 32768.f;
  float mean = st * inv_n;
  float var = s2t * inv_n - mean * mean;
  float rstd = rsqrtf(var + 1e-6f);
#pragma unroll
  for (int o = 0; o < 8; ++o) {
    float gm = gamma[c0 + o], bt = beta[c0 + o];
    float r[4];
#pragma unroll
    for (int p = 0; p < 4; ++p) {
      float gnv = (acc[o][p] - mean) * rstd * gm + bt;
      r[p] = 0.5f * gnv * (1.f + erff(gnv * 0.70710678118654752f));  // exact gelu
    }
    *(float4*)(out + ((size_t)(b * 256 + c0 + o)) * N4 + tid * 4) =
        make_float4(r[0], r[1], r[2], r[3]);
  }
}

// ---------------- fused ffn conv2 (256->4 of 128) + GN + 0.1 residual ------
// grid 256 (b = blk&7, g = blk>>3), 1024 threads, 4 px/thread.
__global__ __launch_bounds__(1024) void k_ffn2gn(const float* __restrict__ in,
                                                 const float* __restrict__ w,
                                                 float* __restrict__ out,
                                                 const float* __restrict__ gamma,
                                                 const float* __restrict__ beta) {
  __shared__ float wl[4 * 256];    // 4 KB
  __shared__ float sred[16], s2red[16];
  int blk = blockIdx.x;
  int b = blk & 7, g = blk >> 3;
  int tid = threadIdx.x;
  int c0 = g * 4;
  const float* wsrc = w + (size_t)c0 * 256;
  if (tid < 1024) wl[tid] = wsrc[tid];
  __syncthreads();
  const float* inb = in + (size_t)b * 256 * N4 + tid * 4;
  float acc[4][4];
#pragma unroll
  for (int o = 0; o < 4; ++o)
#pragma unroll
    for (int p = 0; p < 4; ++p) acc[o][p] = 0.f;
#pragma unroll 4
  for (int c = 0; c < 256; ++c) {
    float4 v = *(const float4*)(inb + (size_t)c * N4);
#pragma unroll
    for (int o = 0; o < 4; ++o) {
      float wv = wl[o * 256 + c];
      acc[o][0] = fmaf(wv, v.x, acc[o][0]);
      acc[o][1] = fmaf(wv, v.y, acc[o][1]);
      acc[o][2] = fmaf(wv, v.z, acc[o][2]);
      acc[o][3] = fmaf(wv, v.w, acc[o][3]);
    }
  }
  float s = 0.f, s2 = 0.f;
#pragma unroll
  for (int o = 0; o < 4; ++o)
#pragma unroll
    for (int p = 0; p < 4; ++p) { s += acc[o][p]; s2 += acc[o][p] * acc[o][p]; }
#pragma unroll
  for (int off = 32; off > 0; off >>= 1) {
    s += __shfl_xor(s, off);
    s2 += __shfl_xor(s2, off);
  }
  int wv = tid >> 6;
  if ((tid & 63) == 0) { sred[wv] = s; s2red[wv] = s2; }
  __syncthreads();
  float st = 0.f, s2t = 0.f;
#pragma unroll
  for (int k = 0; k < 16; ++k) { st += sred[k]; s2t += s2red[k]; }
  float inv_n = 1.f / 16384.f;
  float mean = st * inv_n;
  float var = s2t * inv_n - mean * mean;
  float rstd = rsqrtf(var + 1e-6f);
#pragma unroll
  for (int o = 0; o < 4; ++o) {
    float gm = gamma[c0 + o], bt = beta[c0 + o];
    float* op = out + ((size_t)(b * CC + c0 + o)) * N4 + tid * 4;
    float4 rr = *(const float4*)op;
    float4 ov;
    ov.x = rr.x + 0.1f * ((acc[o][0] - mean) * rstd * gm + bt);
    ov.y = rr.y + 0.1f * ((acc[o][1] - mean) * rstd * gm + bt);
    ov.z = rr.z + 0.1f * ((acc[o][2] - mean) * rstd * gm + bt);
    ov.w = rr.w + 0.1f * ((acc[o][3] - mean) * rstd * gm + bt);
    *(float4*)op = ov;
  }
}

// ---------------- K6: IWT + residual ----------------
__global__ __launch_bounds__(256) void k_iwt(const float* __restrict__ x,
                                             const float* __restrict__ s1,
                                             const float* __restrict__ hout,
                                             float* __restrict__ out) {
  int idx = blockIdx.x * 256 + threadIdx.x;  // B*C*32*32
  int w = idx & 31, h = (idx >> 5) & 31, c = (idx >> 10) & 127, b = idx >> 17;
  int n = h * 32 + w;
  float ll = s1[(size_t)(b * CC + c) * NPIX + n];
  float lh = hout[((size_t)b * C3 + c) * NPIX + n];
  float hl = hout[((size_t)b * C3 + CC + c) * NPIX + n];
  float hh = hout[((size_t)b * C3 + 2 * CC + c) * NPIX + n];
  float va = ll - lh - hl + hh;
  float vb = ll - lh + hl - hh;
  float vc = ll + lh - hl - hh;
  float vd = ll + lh + hl + hh;
  size_t xb = ((size_t)(b * CC + c) * HH + 2 * h) * HH + 2 * w;
  out[xb]          = x[xb]          + 0.1f * va;
  out[xb + 1]      = x[xb + 1]      + 0.1f * vc;
  out[xb + HH]     = x[xb + HH]     + 0.1f * vb;
  out[xb + HH + 1] = x[xb + HH + 1] + 0.1f * vd;
}

extern "C" void kernel_launch(void* const* d_in, const int* in_sizes, int n_in,
                              void* d_out, int out_size, void* d_ws, size_t ws_size,
                              hipStream_t stream) {
  const float* x         = (const float*)d_in[0];
  const float* qkv_w     = (const float*)d_in[1];
  const float* proj_w    = (const float*)d_in[2];
  const float* attn_gn_g = (const float*)d_in[3];
  const float* attn_gn_b = (const float*)d_in[4];
  const float* he_dw_w   = (const float*)d_in[5];
  const float* he_gn1_g  = (const float*)d_in[6];
  const float* he_gn1_b  = (const float*)d_in[7];
  const float* he_pw_w   = (const float*)d_in[8];
  const float* he_gn2_g  = (const float*)d_in[9];
  const float* he_gn2_b  = (const float*)d_in[10];
  const float* alpha     = (const float*)d_in[11];
  const float* ffn_w1    = (const float*)d_in[12];
  const float* ffn_gn1_g = (const float*)d_in[13];
  const float* ffn_gn1_b = (const float*)d_in[14];
  const float* ffn_w2    = (const float*)d_in[15];
  const float* ffn_gn2_g = (const float*)d_in[16];
  const float* ffn_gn2_b = (const float*)d_in[17];
  float* out = (float*)d_out;

  float* ws = (float*)d_ws;
  float* ll   = ws;              // 1,048,576
  float* high = ws + 1048576;    // 3,145,728
  float* qkv  = ws + 4194304;    // 3,145,728 ; reused as y1
  float* qnkv = ws + 7340032;    // 3,145,728 ; qh|kh|vt (fp16) ; reused as pw
  float* atto = ws + 10485760;   // 1,048,576
  float* proj = ws + 11534336;   // 1,048,576
  float* f1   = ws + 12582912;   // 8,388,608
  uint4* qh = (uint4*)qnkv;
  uint4* kh = (uint4*)(qnkv + 524288);
  uint16_t* vt = (uint16_t*)(qnkv + 1048576);   // [bh][16][1024] fp16
  float* y1 = qkv;
  float* pw = qnkv;

  // 1) DWT
  k_dwt<<<4096, 256, 0, stream>>>(x, ll, high);
  // 2) qkv = conv1x1(ll, qkv_w); split + l2norm -> packed fp16 (+ V^T)
  k_conv1x1<128, 1, 8><<<dim3(4, 48, 8), 256, 0, stream>>>(ll, qkv_w, qkv, 384, 1024);
  k_qkvnorm<<<256, 256, 0, stream>>>(qkv, qh, kh, vt);
  // 3) sparse attention (MFMA, 4-wave split-K, 16 q-rows per block)
  k_attn<<<4096, 256, 0, stream>>>((const uint16_t*)qh, (const uint16_t*)kh, vt, atto);
  // 4) fused proj conv + groupnorm + ll residual
  k_projgn<<<256, 1024, 0, stream>>>(atto, proj_w, ll, proj, attn_gn_g, attn_gn_b);
  // 5) high enhance: fused dwconv+gn+silu, then fused pw+gn+alpha residual
  k_dwgn<<<256, 512, 0, stream>>>(high, he_dw_w, y1, he_gn1_g, he_gn1_b);
  k_pwgn<<<256, 1024, 0, stream>>>(y1, he_pw_w, high, pw, he_gn2_g, he_gn2_b, alpha);
  // 6) IWT + residual -> out
  k_iwt<<<4096, 256, 0, stream>>>(x, proj, pw, out);
  // 7) FFN: fused conv1+gn+gelu, fused conv2+gn+0.1 residual
  k_ffn1<<<256, 1024, 0, stream>>>(out, ffn_w1, f1, ffn_gn1_g, ffn_gn1_b);
  k_ffn2gn<<<256, 1024, 0, stream>>>(f1, ffn_w2, out, ffn_gn2_g, ffn_gn2_b);
  (void)in_sizes; (void)n_in; (void)out_size; (void)ws_size;
}

// Round 9
// 349.830 us; speedup vs baseline: 1.1008x; 1.1008x over previous
//
#include <hip/hip_runtime.h>
#include <cstdint>
#include <cstddef>

// Dims (fixed by the problem)
#define BB 8
#define CC 128
#define C3 384
#define HH 64
#define H2 32
#define NPIX 1024   // 32*32
#define N4 4096     // 64*64
#define NHD 8
#define HD 16

typedef _Float16 h2f __attribute__((ext_vector_type(2)));
typedef _Float16 h4f __attribute__((ext_vector_type(4)));
typedef float f4 __attribute__((ext_vector_type(4)));

union U4H { uint4 u; h2f h[4]; };
union H4U { h4f v; h2f h[2]; };

__device__ inline h2f pkrtz(float a, float b) {
  return __builtin_bit_cast(h2f, __builtin_amdgcn_cvt_pkrtz(a, b));
}

// ---------------- K1: Haar DWT ----------------
__global__ __launch_bounds__(256) void k_dwt(const float* __restrict__ x,
                                             float* __restrict__ ll,
                                             float* __restrict__ high) {
  int idx = blockIdx.x * 256 + threadIdx.x;   // B*C*32*32 = 1,048,576
  int w = idx & 31, h = (idx >> 5) & 31, c = (idx >> 10) & 127, b = idx >> 17;
  const float* xp = x + ((size_t)(b * CC + c) * HH + 2 * h) * HH + 2 * w;
  float x1 = xp[0];
  float x2 = xp[HH];
  float x3 = xp[1];
  float x4 = xp[HH + 1];
  int n = h * H2 + w;
  ll[(size_t)(b * CC + c) * NPIX + n]              = 0.5f * ( x1 + x2 + x3 + x4);
  high[((size_t)b * C3 + c) * NPIX + n]            = 0.5f * (-x1 - x2 + x3 + x4);
  high[((size_t)b * C3 + CC + c) * NPIX + n]       = 0.5f * (-x1 + x2 - x3 + x4);
  high[((size_t)b * C3 + 2 * CC + c) * NPIX + n]   = 0.5f * ( x1 - x2 - x3 + x4);
}

// ---------------- conv1x1: register GEMV; OPT outs x P pixels per thread ----
template <int CIN, int P, int OPT>
__global__ __launch_bounds__(256) void k_conv1x1(const float* __restrict__ in,
                                                 const float* __restrict__ w,
                                                 float* __restrict__ out,
                                                 int Cout, int Npix) {
  int tid = threadIdx.x;
  int n0 = (blockIdx.x * 256 + tid) * P;
  int o0 = blockIdx.y * OPT;
  int b = blockIdx.z;
  const float* inb = in + (size_t)b * CIN * Npix + n0;
  const float* wb = w + (size_t)o0 * CIN;
  float acc[OPT][P];
#pragma unroll
  for (int o = 0; o < OPT; ++o)
#pragma unroll
    for (int p = 0; p < P; ++p) acc[o][p] = 0.f;

  for (int c0 = 0; c0 < CIN; c0 += 8) {
#pragma unroll
    for (int c = 0; c < 8; ++c) {
      float vv[P];
      const float* ip = inb + (size_t)(c0 + c) * Npix;
      if constexpr (P == 4) {
        float4 t = *(const float4*)ip;
        vv[0] = t.x; vv[1] = t.y; vv[2] = t.z; vv[3] = t.w;
      } else if constexpr (P == 2) {
        float2 t = *(const float2*)ip;
        vv[0] = t.x; vv[1] = t.y;
      } else {
        vv[0] = ip[0];
      }
#pragma unroll
      for (int o = 0; o < OPT; ++o) {
        float wc = wb[(size_t)o * CIN + c0 + c];   // uniform -> s_load
#pragma unroll
        for (int p = 0; p < P; ++p) acc[o][p] = fmaf(wc, vv[p], acc[o][p]);
      }
    }
  }
  size_t ob = ((size_t)b * Cout + o0) * Npix + n0;
#pragma unroll
  for (int o = 0; o < OPT; ++o) {
    float* op = out + ob + (size_t)o * Npix;
    if constexpr (P == 4) {
      *(float4*)op = make_float4(acc[o][0], acc[o][1], acc[o][2], acc[o][3]);
    } else if constexpr (P == 2) {
      *(float2*)op = make_float2(acc[o][0], acc[o][1]);
    } else {
      op[0] = acc[o][0];
    }
  }
}

// ---------------- K2b: split qkv + l2norm q,k -> fp16; V -> transposed vt ----
__global__ __launch_bounds__(256) void k_qkvnorm(const float* __restrict__ qkv,
                                                 uint4* __restrict__ qh,
                                                 uint4* __restrict__ kh,
                                                 uint16_t* __restrict__ vt) {
  __shared__ uint16_t lds_v[16 * 256];
  int tid = threadIdx.x;
  int idx = blockIdx.x * 256 + tid;  // 65536 = B*NH*NPIX
  int n = idx & 1023, h = (idx >> 10) & 7, b = idx >> 13;
  const float* base = qkv + ((size_t)b * C3 + h * HD) * NPIX + n;
  float q[HD], k[HD], vv[HD];
  float sq = 0.f, sk = 0.f;
#pragma unroll
  for (int d = 0; d < HD; ++d) {
    q[d] = base[(size_t)d * NPIX];
    k[d] = base[(size_t)(CC + d) * NPIX];
    vv[d] = base[(size_t)(2 * CC + d) * NPIX];
    sq += q[d] * q[d];
    sk += k[d] * k[d];
  }
  float rq = 1.f / fmaxf(sqrtf(sq), 1e-12f);
  float rk = 1.f / fmaxf(sqrtf(sk), 1e-12f);
#pragma unroll
  for (int g = 0; g < 2; ++g) {
    U4H pq, pk;
#pragma unroll
    for (int d = 0; d < 4; ++d) {
      int e = g * 8 + 2 * d;
      pq.h[d] = pkrtz(q[e] * rq, q[e + 1] * rq);
      pk.h[d] = pkrtz(k[e] * rk, k[e + 1] * rk);
    }
    qh[(size_t)idx * 2 + g] = pq.u;
    kh[(size_t)idx * 2 + g] = pk.u;
  }
  // V: LDS transpose (256 n  x 16 dims -> 16 rows x 256 n)
#pragma unroll
  for (int d = 0; d < HD; ++d) {
    union { _Float16 f; uint16_t u; } cv;
    cv.f = (_Float16)vv[d];
    lds_v[d * 256 + tid] = cv.u;
  }
  __syncthreads();
  int bh = idx >> 10;                      // block-uniform
  int n0 = (blockIdx.x * 256) & 1023;      // block-uniform
  const uint32_t* ldw = (const uint32_t*)lds_v;
  uint32_t* vtw = (uint32_t*)(vt + (size_t)bh * 16384 + n0);
#pragma unroll
  for (int r = 0; r < 8; ++r) {
    int d = 2 * r + (tid >> 7);
    int c = tid & 127;
    vtw[(size_t)d * 512 + c] = ldw[d * 128 + c];
  }
}

// ---------------- K3: sparse top-k attention via MFMA, 4-wave split-K ----
// (verified round-5 kernel, unchanged)
__global__ __launch_bounds__(256) void k_attn(const uint16_t* __restrict__ qh,
                                              const uint16_t* __restrict__ kh,
                                              const uint16_t* __restrict__ vt,
                                              float* __restrict__ attn_out) {
  __shared__ int cnt_lds[12 * 64];     // [it][lm][w]
  __shared__ float sum_lds[64];        // [lm][w]
  __shared__ f4 obuf[4 * 64];          // [w][lane]
  int tid = threadIdx.x;
  int lane = tid & 63;
  int w = tid >> 6;
  int blk = blockIdx.x;                // 4096 blocks: 64 per (b,h)
  int bh = blk >> 6;
  int q0 = (blk & 63) << 4;
  int lm = lane & 15;
  int lg = lane >> 4;
  int b = bh >> 3, h = bh & 7;

  H4U bq;
  bq.v = *(const h4f*)(qh + ((size_t)bh * 1024 + q0 + lm) * 16 + 4 * lg);
  const h2f qsc = {(_Float16)0.25f, (_Float16)0.25f};
  bq.h[0] *= qsc;
  bq.h[1] *= qsc;

  const f4 z = {0.f, 0.f, 0.f, 0.f};
  const uint16_t* kbase = kh + (size_t)bh * 16384 + 4 * lg;
  h2f sc[16][2];
#pragma unroll
  for (int j = 0; j < 16; ++j) {
    int J = (w << 4) | j;
    h4f ak = *(const h4f*)(kbase + (size_t)(16 * J + lm) * 16); // A[m=krow][k=hd]
    f4 d = __builtin_amdgcn_mfma_f32_16x16x16f16(ak, bq.v, z, 0, 0, 0);
    sc[j][0] = pkrtz(d[0], d[1]);
    sc[j][1] = pkrtz(d[2], d[3]);
  }

  float lo = -0.26f, hi = 0.26f;
  _Float16 hlo = (_Float16)(-0.26f);
#pragma unroll 1
  for (int it = 0; it < 12; ++it) {
    float mid = 0.5f * (lo + hi);
    _Float16 hm = (_Float16)mid;
    int c = 0;
#pragma unroll
    for (int j = 0; j < 16; ++j) {
      c += (sc[j][0][0] >= hm);
      c += (sc[j][0][1] >= hm);
      c += (sc[j][1][0] >= hm);
      c += (sc[j][1][1] >= hm);
    }
    c += __shfl_xor(c, 16);
    c += __shfl_xor(c, 32);
    if (lg == 0) cnt_lds[it * 64 + lm * 4 + w] = c;
    __syncthreads();
    int4 c4 = *(const int4*)&cnt_lds[it * 64 + lm * 4];
    int ct = (c4.x + c4.y) + (c4.z + c4.w);
    bool ge = (ct >= 512);
    lo = ge ? mid : lo;
    hlo = ge ? hm : hlo;
    hi = ge ? hi : mid;
  }

  float ss = 0.f;
#pragma unroll
  for (int j = 0; j < 16; ++j) {
#pragma unroll
    for (int r = 0; r < 2; ++r) {
      h2f t = sc[j][r];
      float p0 = (t[0] >= hlo) ? __expf((float)t[0]) : 0.f;
      float p1 = (t[1] >= hlo) ? __expf((float)t[1]) : 0.f;
      ss += p0 + p1;
      sc[j][r] = pkrtz(p0, p1);
    }
  }
  ss += __shfl_xor(ss, 16);
  ss += __shfl_xor(ss, 32);
  if (lg == 0) sum_lds[lm * 4 + w] = ss;
  __syncthreads();
  float4 s4 = *(const float4*)&sum_lds[lm * 4];
  float inv = 1.f / ((s4.x + s4.y) + (s4.z + s4.w));

  const uint16_t* vbase = vt + (size_t)bh * 16384 + (size_t)lm * 1024 + 4 * lg;
  f4 acc[2] = {z, z};
#pragma unroll
  for (int j = 0; j < 16; ++j) {
    int J = (w << 4) | j;
    h4f va = *(const h4f*)(vbase + 16 * J);   // A[m=dim][k=krow]
    H4U pf;
    pf.h[0] = sc[j][0];
    pf.h[1] = sc[j][1];                        // B[k=krow][n=q]
    acc[j & 1] = __builtin_amdgcn_mfma_f32_16x16x16f16(va, pf.v, acc[j & 1], 0, 0, 0);
  }
  f4 o = acc[0] + acc[1];
  obuf[(w << 6) | lane] = o;
  __syncthreads();
  if (w == 0) {
    f4 t = obuf[lane] + obuf[64 + lane] + obuf[128 + lane] + obuf[192 + lane];
#pragma unroll
    for (int e = 0; e < 4; ++e) {
      int dim = 4 * lg + e;
      attn_out[((size_t)(b * CC + h * HD + dim) * NPIX) + q0 + lm] = t[e] * inv;
    }
  }
}

// ---------------- fused proj conv (128->4 of 128) + GN + ll residual -------
// grid 256 (b = blk&7, g = blk>>3), 1024 threads, 1 px/thread.
// Weights read via uniform global loads -> s_load (scalar path, no LDS tax).
__global__ __launch_bounds__(1024) void k_projgn(const float* __restrict__ in,
                                                 const float* __restrict__ w,
                                                 const float* __restrict__ res,
                                                 float* __restrict__ out,
                                                 const float* __restrict__ gamma,
                                                 const float* __restrict__ beta) {
  __shared__ float sred[16], s2red[16];
  int blk = blockIdx.x;
  int b = blk & 7, g = blk >> 3;
  int tid = threadIdx.x;
  int c0 = g * 4;
  const float* wb = w + (size_t)c0 * CC;
  const float* inb = in + (size_t)b * CC * NPIX + tid;
  float acc[4] = {0.f, 0.f, 0.f, 0.f};
  for (int cc0 = 0; cc0 < 128; cc0 += 8) {
#pragma unroll
    for (int c = 0; c < 8; ++c) {
      float v = inb[(size_t)(cc0 + c) * NPIX];
#pragma unroll
      for (int o = 0; o < 4; ++o)
        acc[o] = fmaf(wb[(size_t)o * CC + cc0 + c], v, acc[o]);
    }
  }
  float s = 0.f, s2 = 0.f;
#pragma unroll
  for (int o = 0; o < 4; ++o) { s += acc[o]; s2 += acc[o] * acc[o]; }
#pragma unroll
  for (int off = 32; off > 0; off >>= 1) {
    s += __shfl_xor(s, off);
    s2 += __shfl_xor(s2, off);
  }
  int wv = tid >> 6;
  if ((tid & 63) == 0) { sred[wv] = s; s2red[wv] = s2; }
  __syncthreads();
  float st = 0.f, s2t = 0.f;
#pragma unroll
  for (int k = 0; k < 16; ++k) { st += sred[k]; s2t += s2red[k]; }
  float inv_n = 1.f / 4096.f;
  float mean = st * inv_n;
  float var = s2t * inv_n - mean * mean;
  float rstd = rsqrtf(var + 1e-6f);
#pragma unroll
  for (int o = 0; o < 4; ++o) {
    size_t base = ((size_t)b * CC + c0 + o) * NPIX + tid;
    out[base] = res[base] + ((acc[o] - mean) * rstd * gamma[c0 + o] + beta[c0 + o]);
  }
}

// ---------------- fused depthwise 3x3 + GN + SiLU (512 thr, 2 px/thread) ----
__global__ __launch_bounds__(512) void k_dwgn(const float* __restrict__ in,
                                              const float* __restrict__ w,
                                              float* __restrict__ out,
                                              const float* __restrict__ gamma,
                                              const float* __restrict__ beta) {
  __shared__ float xs[12 * 1152];      // 12 ch x 32 rows x 36 stride = 55.3 KB
  __shared__ float sred[8], s2red[8];
  int blk = blockIdx.x;
  int b = blk & 7, g = blk >> 3;
  int tid = threadIdx.x;
  int c0 = g * 12;
  const float* inb = in + ((size_t)b * C3 + c0) * NPIX;
  // stage: 12288 floats = 6 f4/thread, scatter to padded rows
#pragma unroll
  for (int k = 0; k < 6; ++k) {
    int e = (k * 512 + tid) * 4;
    int cc = e >> 10, rem = e & 1023;
    int row = rem >> 5, col = rem & 31;
    float4 v = *(const float4*)(inb + e);
    *(float4*)&xs[cc * 1152 + row * 36 + col] = v;
  }
  __syncthreads();
  int n0 = tid * 2;
  int i = n0 >> 5, j0 = n0 & 31;
  float acc[12][2];
  float s = 0.f, s2 = 0.f;
#pragma unroll
  for (int cc = 0; cc < 12; ++cc) {
    const float* wc = w + (size_t)(c0 + cc) * 9;
    float w0 = wc[0], w1 = wc[1], w2 = wc[2], w3 = wc[3], w4 = wc[4],
          w5 = wc[5], w6 = wc[6], w7 = wc[7], w8 = wc[8];
    float r[3][4];
#pragma unroll
    for (int di = 0; di < 3; ++di) {
      int ii = i + di - 1;
      bool rv = (ii >= 0 && ii < 32);
#pragma unroll
      for (int dj = 0; dj < 4; ++dj) {
        int jj = j0 + dj - 1;
        r[di][dj] = (rv && jj >= 0 && jj < 32) ? xs[cc * 1152 + ii * 36 + jj] : 0.f;
      }
    }
#pragma unroll
    for (int p = 0; p < 2; ++p) {
      float a = r[0][p] * w0 + r[0][p + 1] * w1 + r[0][p + 2] * w2
              + r[1][p] * w3 + r[1][p + 1] * w4 + r[1][p + 2] * w5
              + r[2][p] * w6 + r[2][p + 1] * w7 + r[2][p + 2] * w8;
      acc[cc][p] = a;
      s += a;
      s2 += a * a;
    }
  }
  // block reduce (8 waves)
#pragma unroll
  for (int off = 32; off > 0; off >>= 1) {
    s += __shfl_xor(s, off);
    s2 += __shfl_xor(s2, off);
  }
  int wv = tid >> 6;
  if ((tid & 63) == 0) { sred[wv] = s; s2red[wv] = s2; }
  __syncthreads();
  float st = 0.f, s2t = 0.f;
#pragma unroll
  for (int k = 0; k < 8; ++k) { st += sred[k]; s2t += s2red[k]; }
  float inv_n = 1.f / 12288.f;
  float mean = st * inv_n;
  float var = s2t * inv_n - mean * mean;
  float rstd = rsqrtf(var + 1e-6f);
#pragma unroll
  for (int cc = 0; cc < 12; ++cc) {
    float2 o;
#pragma unroll
    for (int p = 0; p < 2; ++p) {
      float gnv = (acc[cc][p] - mean) * rstd * gamma[c0 + cc] + beta[c0 + cc];
      ((float*)&o)[p] = gnv / (1.f + __expf(-gnv));   // silu
    }
    *(float2*)(out + ((size_t)b * C3 + c0 + cc) * NPIX + n0) = o;
  }
}

// ---------------- fused pw conv (384->12 of 384) + GN + alpha residual ------
// grid 256 (b = blk&7, g = blk>>3), 1024 threads, 1 px/thread.
// Weights via uniform global loads -> s_load (scalar path).
__global__ __launch_bounds__(1024) void k_pwgn(const float* __restrict__ in,
                                               const float* __restrict__ w,
                                               const float* __restrict__ res,
                                               float* __restrict__ out,
                                               const float* __restrict__ gamma,
                                               const float* __restrict__ beta,
                                               const float* __restrict__ alpha_ptr) {
  __shared__ float sred[16], s2red[16];
  int blk = blockIdx.x;
  int b = blk & 7, g = blk >> 3;
  int tid = threadIdx.x;
  int c0 = g * 12;
  const float* wb = w + (size_t)c0 * C3;
  const float* inb = in + (size_t)b * C3 * NPIX + tid;
  float acc[12];
#pragma unroll
  for (int o = 0; o < 12; ++o) acc[o] = 0.f;
  for (int cc0 = 0; cc0 < 384; cc0 += 8) {
#pragma unroll
    for (int c = 0; c < 8; ++c) {
      float v = inb[(size_t)(cc0 + c) * NPIX];
#pragma unroll
      for (int o = 0; o < 12; ++o)
        acc[o] = fmaf(wb[(size_t)o * C3 + cc0 + c], v, acc[o]);
    }
  }
  float s = 0.f, s2 = 0.f;
#pragma unroll
  for (int o = 0; o < 12; ++o) { s += acc[o]; s2 += acc[o] * acc[o]; }
#pragma unroll
  for (int off = 32; off > 0; off >>= 1) {
    s += __shfl_xor(s, off);
    s2 += __shfl_xor(s2, off);
  }
  int wv = tid >> 6;
  if ((tid & 63) == 0) { sred[wv] = s; s2red[wv] = s2; }
  __syncthreads();
  float st = 0.f, s2t = 0.f;
#pragma unroll
  for (int k = 0; k < 16; ++k) { st += sred[k]; s2t += s2red[k]; }
  float inv_n = 1.f / 12288.f;
  float mean = st * inv_n;
  float var = s2t * inv_n - mean * mean;
  float rstd = rsqrtf(var + 1e-6f);
  float a = alpha_ptr[0];
#pragma unroll
  for (int o = 0; o < 12; ++o) {
    size_t base = ((size_t)b * C3 + c0 + o) * NPIX + tid;
    out[base] = res[base] + a * ((acc[o] - mean) * rstd * gamma[c0 + o] + beta[c0 + o]);
  }
}

// ---------------- fused ffn conv1 (128->8 of 256) + GN + GELU ----------------
// grid 256 (b = blk&7, g = blk>>3), 1024 threads, 4 px/thread.
// Weights via uniform global loads -> s_load (scalar path).
__global__ __launch_bounds__(1024) void k_ffn1(const float* __restrict__ in,
                                               const float* __restrict__ w,
                                               float* __restrict__ out,
                                               const float* __restrict__ gamma,
                                               const float* __restrict__ beta) {
  __shared__ float sred[16], s2red[16];
  int blk = blockIdx.x;
  int b = blk & 7, g = blk >> 3;
  int tid = threadIdx.x;
  int c0 = g * 8;
  const float* wb = w + (size_t)c0 * CC;
  const float* inb = in + (size_t)b * CC * N4 + tid * 4;
  float acc[8][4];
#pragma unroll
  for (int o = 0; o < 8; ++o)
#pragma unroll
    for (int p = 0; p < 4; ++p) acc[o][p] = 0.f;
  for (int cc0 = 0; cc0 < 128; cc0 += 8) {
#pragma unroll
    for (int c = 0; c < 8; ++c) {
      float4 v = *(const float4*)(inb + (size_t)(cc0 + c) * N4);
#pragma unroll
      for (int o = 0; o < 8; ++o) {
        float wv = wb[(size_t)o * CC + cc0 + c];
        acc[o][0] = fmaf(wv, v.x, acc[o][0]);
        acc[o][1] = fmaf(wv, v.y, acc[o][1]);
        acc[o][2] = fmaf(wv, v.z, acc[o][2]);
        acc[o][3] = fmaf(wv, v.w, acc[o][3]);
      }
    }
  }
  float s = 0.f, s2 = 0.f;
#pragma unroll
  for (int o = 0; o < 8; ++o)
#pragma unroll
    for (int p = 0; p < 4; ++p) { s += acc[o][p]; s2 += acc[o][p] * acc[o][p]; }
#pragma unroll
  for (int off = 32; off > 0; off >>= 1) {
    s += __shfl_xor(s, off);
    s2 += __shfl_xor(s2, off);
  }
  int wv = tid >> 6;
  if ((tid & 63) == 0) { sred[wv] = s; s2red[wv] = s2; }
  __syncthreads();
  float st = 0.f, s2t = 0.f;
#pragma unroll
  for (int k = 0; k < 16; ++k) { st += sred[k]; s2t += s2red[k]; }
  float inv_n = 1.f / 32768.f;
  float mean = st * inv_n;
  float var = s2t * inv_n - mean * mean;
  float rstd = rsqrtf(var + 1e-6f);
#pragma unroll
  for (int o = 0; o < 8; ++o) {
    float gm = gamma[c0 + o], bt = beta[c0 + o];
    float r[4];
#pragma unroll
    for (int p = 0; p < 4; ++p) {
      float gnv = (acc[o][p] - mean) * rstd * gm + bt;
      r[p] = 0.5f * gnv * (1.f + erff(gnv * 0.70710678118654752f));  // exact gelu
    }
    *(float4*)(out + ((size_t)(b * 256 + c0 + o)) * N4 + tid * 4) =
        make_float4(r[0], r[1], r[2], r[3]);
  }
}

// ---------------- fused ffn conv2 (256->4 of 128) + GN + 0.1 residual ------
// grid 256 (b = blk&7, g = blk>>3), 1024 threads, 4 px/thread.
// Weights via uniform global loads -> s_load (scalar path).
__global__ __launch_bounds__(1024) void k_ffn2gn(const float* __restrict__ in,
                                                 const float* __restrict__ w,
                                                 float* __restrict__ out,
                                                 const float* __restrict__ gamma,
                                                 const float* __restrict__ beta) {
  __shared__ float sred[16], s2red[16];
  int blk = blockIdx.x;
  int b = blk & 7, g = blk >> 3;
  int tid = threadIdx.x;
  int c0 = g * 4;
  const float* wb = w + (size_t)c0 * 256;
  const float* inb = in + (size_t)b * 256 * N4 + tid * 4;
  float acc[4][4];
#pragma unroll
  for (int o = 0; o < 4; ++o)
#pragma unroll
    for (int p = 0; p < 4; ++p) acc[o][p] = 0.f;
  for (int cc0 = 0; cc0 < 256; cc0 += 8) {
#pragma unroll
    for (int c = 0; c < 8; ++c) {
      float4 v = *(const float4*)(inb + (size_t)(cc0 + c) * N4);
#pragma unroll
      for (int o = 0; o < 4; ++o) {
        float wv = wb[(size_t)o * 256 + cc0 + c];
        acc[o][0] = fmaf(wv, v.x, acc[o][0]);
        acc[o][1] = fmaf(wv, v.y, acc[o][1]);
        acc[o][2] = fmaf(wv, v.z, acc[o][2]);
        acc[o][3] = fmaf(wv, v.w, acc[o][3]);
      }
    }
  }
  float s = 0.f, s2 = 0.f;
#pragma unroll
  for (int o = 0; o < 4; ++o)
#pragma unroll
    for (int p = 0; p < 4; ++p) { s += acc[o][p]; s2 += acc[o][p] * acc[o][p]; }
#pragma unroll
  for (int off = 32; off > 0; off >>= 1) {
    s += __shfl_xor(s, off);
    s2 += __shfl_xor(s2, off);
  }
  int wv = tid >> 6;
  if ((tid & 63) == 0) { sred[wv] = s; s2red[wv] = s2; }
  __syncthreads();
  float st = 0.f, s2t = 0.f;
#pragma unroll
  for (int k = 0; k < 16; ++k) { st += sred[k]; s2t += s2red[k]; }
  float inv_n = 1.f / 16384.f;
  float mean = st * inv_n;
  float var = s2t * inv_n - mean * mean;
  float rstd = rsqrtf(var + 1e-6f);
#pragma unroll
  for (int o = 0; o < 4; ++o) {
    float gm = gamma[c0 + o], bt = beta[c0 + o];
    float* op = out + ((size_t)(b * CC + c0 + o)) * N4 + tid * 4;
    float4 rr = *(const float4*)op;
    float4 ov;
    ov.x = rr.x + 0.1f * ((acc[o][0] - mean) * rstd * gm + bt);
    ov.y = rr.y + 0.1f * ((acc[o][1] - mean) * rstd * gm + bt);
    ov.z = rr.z + 0.1f * ((acc[o][2] - mean) * rstd * gm + bt);
    ov.w = rr.w + 0.1f * ((acc[o][3] - mean) * rstd * gm + bt);
    *(float4*)op = ov;
  }
}

// ---------------- K6: IWT + residual ----------------
__global__ __launch_bounds__(256) void k_iwt(const float* __restrict__ x,
                                             const float* __restrict__ s1,
                                             const float* __restrict__ hout,
                                             float* __restrict__ out) {
  int idx = blockIdx.x * 256 + threadIdx.x;  // B*C*32*32
  int w = idx & 31, h = (idx >> 5) & 31, c = (idx >> 10) & 127, b = idx >> 17;
  int n = h * 32 + w;
  float ll = s1[(size_t)(b * CC + c) * NPIX + n];
  float lh = hout[((size_t)b * C3 + c) * NPIX + n];
  float hl = hout[((size_t)b * C3 + CC + c) * NPIX + n];
  float hh = hout[((size_t)b * C3 + 2 * CC + c) * NPIX + n];
  float va = ll - lh - hl + hh;
  float vb = ll - lh + hl - hh;
  float vc = ll + lh - hl - hh;
  float vd = ll + lh + hl + hh;
  size_t xb = ((size_t)(b * CC + c) * HH + 2 * h) * HH + 2 * w;
  out[xb]          = x[xb]          + 0.1f * va;
  out[xb + 1]      = x[xb + 1]      + 0.1f * vc;
  out[xb + HH]     = x[xb + HH]     + 0.1f * vb;
  out[xb + HH + 1] = x[xb + HH + 1] + 0.1f * vd;
}

extern "C" void kernel_launch(void* const* d_in, const int* in_sizes, int n_in,
                              void* d_out, int out_size, void* d_ws, size_t ws_size,
                              hipStream_t stream) {
  const float* x         = (const float*)d_in[0];
  const float* qkv_w     = (const float*)d_in[1];
  const float* proj_w    = (const float*)d_in[2];
  const float* attn_gn_g = (const float*)d_in[3];
  const float* attn_gn_b = (const float*)d_in[4];
  const float* he_dw_w   = (const float*)d_in[5];
  const float* he_gn1_g  = (const float*)d_in[6];
  const float* he_gn1_b  = (const float*)d_in[7];
  const float* he_pw_w   = (const float*)d_in[8];
  const float* he_gn2_g  = (const float*)d_in[9];
  const float* he_gn2_b  = (const float*)d_in[10];
  const float* alpha     = (const float*)d_in[11];
  const float* ffn_w1    = (const float*)d_in[12];
  const float* ffn_gn1_g = (const float*)d_in[13];
  const float* ffn_gn1_b = (const float*)d_in[14];
  const float* ffn_w2    = (const float*)d_in[15];
  const float* ffn_gn2_g = (const float*)d_in[16];
  const float* ffn_gn2_b = (const float*)d_in[17];
  float* out = (float*)d_out;

  float* ws = (float*)d_ws;
  float* ll   = ws;              // 1,048,576
  float* high = ws + 1048576;    // 3,145,728
  float* qkv  = ws + 4194304;    // 3,145,728 ; reused as y1
  float* qnkv = ws + 7340032;    // 3,145,728 ; qh|kh|vt (fp16) ; reused as pw
  float* atto = ws + 10485760;   // 1,048,576
  float* proj = ws + 11534336;   // 1,048,576
  float* f1   = ws + 12582912;   // 8,388,608
  uint4* qh = (uint4*)qnkv;
  uint4* kh = (uint4*)(qnkv + 524288);
  uint16_t* vt = (uint16_t*)(qnkv + 1048576);   // [bh][16][1024] fp16
  float* y1 = qkv;
  float* pw = qnkv;

  // 1) DWT
  k_dwt<<<4096, 256, 0, stream>>>(x, ll, high);
  // 2) qkv = conv1x1(ll, qkv_w); split + l2norm -> packed fp16 (+ V^T)
  k_conv1x1<128, 1, 8><<<dim3(4, 48, 8), 256, 0, stream>>>(ll, qkv_w, qkv, 384, 1024);
  k_qkvnorm<<<256, 256, 0, stream>>>(qkv, qh, kh, vt);
  // 3) sparse attention (MFMA, 4-wave split-K, 16 q-rows per block)
  k_attn<<<4096, 256, 0, stream>>>((const uint16_t*)qh, (const uint16_t*)kh, vt, atto);
  // 4) fused proj conv + groupnorm + ll residual
  k_projgn<<<256, 1024, 0, stream>>>(atto, proj_w, ll, proj, attn_gn_g, attn_gn_b);
  // 5) high enhance: fused dwconv+gn+silu, then fused pw+gn+alpha residual
  k_dwgn<<<256, 512, 0, stream>>>(high, he_dw_w, y1, he_gn1_g, he_gn1_b);
  k_pwgn<<<256, 1024, 0, stream>>>(y1, he_pw_w, high, pw, he_gn2_g, he_gn2_b, alpha);
  // 6) IWT + residual -> out
  k_iwt<<<4096, 256, 0, stream>>>(x, proj, pw, out);
  // 7) FFN: fused conv1+gn+gelu, fused conv2+gn+0.1 residual
  k_ffn1<<<256, 1024, 0, stream>>>(out, ffn_w1, f1, ffn_gn1_g, ffn_gn1_b);
  k_ffn2gn<<<256, 1024, 0, stream>>>(f1, ffn_w2, out, ffn_gn2_g, ffn_gn2_b);
  (void)in_sizes; (void)n_in; (void)out_size; (void)ws_size;
}